// Round 4
// baseline (96.107 us; speedup 1.0000x reference)
//
#include <hip/hip_runtime.h>

#define SIGMA_INV 1.0e4f
#define GAMMA_INV 1.0e4f
#define ZNEARC 0.1f
#define ZFARC 50.0f
#define EPSV 1e-10f

typedef float f32x4 __attribute__((ext_vector_type(4)));
typedef int   i32x4 __attribute__((ext_vector_type(4)));

__global__ __launch_bounds__(256) void softblend_kernel(
    const float* __restrict__ texels,
    const float* __restrict__ dists,
    const float* __restrict__ zbuf,
    const int*   __restrict__ pix,
    float* __restrict__ out,
    int npix)
{
    const int i = blockIdx.x * blockDim.x + threadIdx.x;
    if (i >= npix) return;

    const f32x4* dp = reinterpret_cast<const f32x4*>(dists + (size_t)i * 8);
    const f32x4* zp = reinterpret_cast<const f32x4*>(zbuf + (size_t)i * 8);
    const i32x4* pp = reinterpret_cast<const i32x4*>(pix + (size_t)i * 8);
    const f32x4* tp = reinterpret_cast<const f32x4*>(texels + (size_t)i * 24);

    // texels: 201 MB, zero reuse -> nontemporal (evict-first) so the three
    // small arrays (dists/zbuf/pix = 201 MB) stay resident in the 256 MB L3.
    f32x4 t0 = __builtin_nontemporal_load(tp + 0);
    f32x4 t1 = __builtin_nontemporal_load(tp + 1);
    f32x4 t2 = __builtin_nontemporal_load(tp + 2);
    f32x4 t3 = __builtin_nontemporal_load(tp + 3);
    f32x4 t4 = __builtin_nontemporal_load(tp + 4);
    f32x4 t5 = __builtin_nontemporal_load(tp + 5);

    f32x4 dv0 = dp[0], dv1 = dp[1];
    f32x4 zv0 = zp[0], zv1 = zp[1];
    i32x4 pv0 = pp[0], pv1 = pp[1];

    const float zscale = 1.0f / (ZFARC - ZNEARC);

    float d[8] = {dv0.x, dv0.y, dv0.z, dv0.w, dv1.x, dv1.y, dv1.z, dv1.w};
    float z[8] = {zv0.x, zv0.y, zv0.z, zv0.w, zv1.x, zv1.y, zv1.z, zv1.w};
    int   p[8] = {pv0.x, pv0.y, pv0.z, pv0.w, pv1.x, pv1.y, pv1.z, pv1.w};

    float prob[8], zinv[8];
    float zmax = EPSV;
    float alpha = 1.0f;
    #pragma unroll
    for (int k = 0; k < 8; ++k) {
        const bool m = p[k] >= 0;
        const float pr = m ? 1.0f / (1.0f + __expf(d[k] * SIGMA_INV)) : 0.0f;
        prob[k] = pr;
        alpha *= (1.0f - pr);
        const float zi = m ? (ZFARC - z[k]) * zscale : 0.0f;
        zinv[k] = zi;
        zmax = fmaxf(zmax, zi);
    }

    const float delta = fmaxf(__expf((EPSV - zmax) * GAMMA_INV), EPSV);
    float denom = delta;
    float wn[8];
    #pragma unroll
    for (int k = 0; k < 8; ++k) {
        const float w = prob[k] * __expf((zinv[k] - zmax) * GAMMA_INV);
        wn[k] = w;
        denom += w;
    }
    const float inv = 1.0f / denom;

    const float tf[24] = {t0.x, t0.y, t0.z, t0.w, t1.x, t1.y, t1.z, t1.w,
                          t2.x, t2.y, t2.z, t2.w, t3.x, t3.y, t3.z, t3.w,
                          t4.x, t4.y, t4.z, t4.w, t5.x, t5.y, t5.z, t5.w};

    // BG = (1,1,1): rgb_c = (sum_k wn_k * tex_kc + delta) / denom
    float r = delta, g = delta, b = delta;
    #pragma unroll
    for (int k = 0; k < 8; ++k) {
        r += wn[k] * tf[k * 3 + 0];
        g += wn[k] * tf[k * 3 + 1];
        b += wn[k] * tf[k * 3 + 2];
    }

    f32x4 o;
    o.x = r * inv;
    o.y = g * inv;
    o.z = b * inv;
    o.w = 1.0f - alpha;
    __builtin_nontemporal_store(o, reinterpret_cast<f32x4*>(out) + i);
}

extern "C" void kernel_launch(void* const* d_in, const int* in_sizes, int n_in,
                              void* d_out, int out_size, void* d_ws, size_t ws_size,
                              hipStream_t stream) {
    const float* texels = (const float*)d_in[0];
    const float* dists  = (const float*)d_in[1];
    const float* zbuf   = (const float*)d_in[2];
    const int*   pix    = (const int*)d_in[3];
    float* out = (float*)d_out;

    const int npix = in_sizes[1] / 8;  // dists is [N,H,W,K=8]
    const int block = 256;
    const int grid = (npix + block - 1) / block;
    softblend_kernel<<<grid, block, 0, stream>>>(texels, dists, zbuf, pix, out, npix);
}

// Round 5
// 89.633 us; speedup vs baseline: 1.0722x; 1.0722x over previous
//
#include <hip/hip_runtime.h>

#define SIGMA_INV 1.0e4f
#define GAMMA_INV 1.0e4f
#define ZNEARC 0.1f
#define ZFARC 50.0f
#define EPSV 1e-10f

typedef float f32x4 __attribute__((ext_vector_type(4)));
typedef int   i32x4 __attribute__((ext_vector_type(4)));

__global__ __launch_bounds__(256) void softblend_kernel(
    const float* __restrict__ texels,
    const float* __restrict__ dists,
    const float* __restrict__ zbuf,
    const int*   __restrict__ pix,
    float* __restrict__ out,
    int npair)   // each thread = 2 adjacent pixels
{
    const int i = blockIdx.x * blockDim.x + threadIdx.x;
    if (i >= npair) return;

    const f32x4* dp = reinterpret_cast<const f32x4*>(dists + (size_t)i * 16);
    const f32x4* zp = reinterpret_cast<const f32x4*>(zbuf + (size_t)i * 16);
    const i32x4* pp = reinterpret_cast<const i32x4*>(pix + (size_t)i * 16);
    const f32x4* tp = reinterpret_cast<const f32x4*>(texels + (size_t)i * 48);

    // Issue all 20 loads up front (2 pixels' worth) — deep MLP per wave.
    f32x4 dv0 = dp[0], dv1 = dp[1], dv2 = dp[2], dv3 = dp[3];
    f32x4 zv0 = zp[0], zv1 = zp[1], zv2 = zp[2], zv3 = zp[3];
    i32x4 pv0 = pp[0], pv1 = pp[1], pv2 = pp[2], pv3 = pp[3];
    f32x4 t0 = tp[0], t1 = tp[1], t2 = tp[2],  t3 = tp[3],  t4 = tp[4],  t5 = tp[5];
    f32x4 t6 = tp[6], t7 = tp[7], t8 = tp[8],  t9 = tp[9],  t10 = tp[10], t11 = tp[11];

    const float zscale = 1.0f / (ZFARC - ZNEARC);

    const float d[16] = {dv0.x, dv0.y, dv0.z, dv0.w, dv1.x, dv1.y, dv1.z, dv1.w,
                         dv2.x, dv2.y, dv2.z, dv2.w, dv3.x, dv3.y, dv3.z, dv3.w};
    const float z[16] = {zv0.x, zv0.y, zv0.z, zv0.w, zv1.x, zv1.y, zv1.z, zv1.w,
                         zv2.x, zv2.y, zv2.z, zv2.w, zv3.x, zv3.y, zv3.z, zv3.w};
    const int   p[16] = {pv0.x, pv0.y, pv0.z, pv0.w, pv1.x, pv1.y, pv1.z, pv1.w,
                         pv2.x, pv2.y, pv2.z, pv2.w, pv3.x, pv3.y, pv3.z, pv3.w};
    const float tf[48] = {
        t0.x, t0.y, t0.z, t0.w, t1.x, t1.y, t1.z, t1.w, t2.x, t2.y, t2.z, t2.w,
        t3.x, t3.y, t3.z, t3.w, t4.x, t4.y, t4.z, t4.w, t5.x, t5.y, t5.z, t5.w,
        t6.x, t6.y, t6.z, t6.w, t7.x, t7.y, t7.z, t7.w, t8.x, t8.y, t8.z, t8.w,
        t9.x, t9.y, t9.z, t9.w, t10.x, t10.y, t10.z, t10.w, t11.x, t11.y, t11.z, t11.w};

    f32x4* op = reinterpret_cast<f32x4*>(out) + (size_t)i * 2;

    // O is a literal 0/1 -> all array indices constant-fold (no scratch).
    #define PIX_COMPUTE(O)                                                        \
    do {                                                                          \
        float prob[8], zinv[8];                                                   \
        float zmax = EPSV;                                                        \
        float alpha = 1.0f;                                                       \
        _Pragma("unroll")                                                         \
        for (int k = 0; k < 8; ++k) {                                             \
            const bool m = p[(O)*8 + k] >= 0;                                     \
            const float pr = m ? 1.0f / (1.0f + __expf(d[(O)*8 + k] * SIGMA_INV)) \
                               : 0.0f;                                            \
            prob[k] = pr;                                                         \
            alpha *= (1.0f - pr);                                                 \
            const float zi = m ? (ZFARC - z[(O)*8 + k]) * zscale : 0.0f;          \
            zinv[k] = zi;                                                         \
            zmax = fmaxf(zmax, zi);                                               \
        }                                                                         \
        const float delta = fmaxf(__expf((EPSV - zmax) * GAMMA_INV), EPSV);       \
        float denom = delta;                                                      \
        float wn[8];                                                              \
        _Pragma("unroll")                                                         \
        for (int k = 0; k < 8; ++k) {                                             \
            const float w = prob[k] * __expf((zinv[k] - zmax) * GAMMA_INV);       \
            wn[k] = w;                                                            \
            denom += w;                                                           \
        }                                                                         \
        const float inv = 1.0f / denom;                                           \
        float r = delta, g = delta, b = delta;                                    \
        _Pragma("unroll")                                                         \
        for (int k = 0; k < 8; ++k) {                                             \
            r += wn[k] * tf[(O)*24 + k*3 + 0];                                    \
            g += wn[k] * tf[(O)*24 + k*3 + 1];                                    \
            b += wn[k] * tf[(O)*24 + k*3 + 2];                                    \
        }                                                                         \
        f32x4 o;                                                                  \
        o.x = r * inv;                                                            \
        o.y = g * inv;                                                            \
        o.z = b * inv;                                                            \
        o.w = 1.0f - alpha;                                                       \
        __builtin_nontemporal_store(o, op + (O));                                 \
    } while (0)

    PIX_COMPUTE(0);
    PIX_COMPUTE(1);
    #undef PIX_COMPUTE
}

extern "C" void kernel_launch(void* const* d_in, const int* in_sizes, int n_in,
                              void* d_out, int out_size, void* d_ws, size_t ws_size,
                              hipStream_t stream) {
    const float* texels = (const float*)d_in[0];
    const float* dists  = (const float*)d_in[1];
    const float* zbuf   = (const float*)d_in[2];
    const int*   pix    = (const int*)d_in[3];
    float* out = (float*)d_out;

    const int npix = in_sizes[1] / 8;   // dists is [N,H,W,K=8]
    const int npair = npix / 2;         // npix = 2^21, even
    const int block = 256;
    const int grid = (npair + block - 1) / block;
    softblend_kernel<<<grid, block, 0, stream>>>(texels, dists, zbuf, pix, out, npair);
}

// Round 6
// 80.087 us; speedup vs baseline: 1.2000x; 1.1192x over previous
//
#include <hip/hip_runtime.h>

#define SIGMA_INV 1.0e4f
#define GAMMA_INV 1.0e4f
#define ZNEARC 0.1f
#define ZFARC 50.0f
#define EPSV 1e-10f

typedef float f32x4 __attribute__((ext_vector_type(4)));
typedef int   i32x4 __attribute__((ext_vector_type(4)));

__global__ __launch_bounds__(256) void softblend_kernel(
    const float* __restrict__ texels,
    const float* __restrict__ dists,
    const float* __restrict__ zbuf,
    const int*   __restrict__ pix,
    float* __restrict__ out,
    int npix)
{
    const int i = blockIdx.x * blockDim.x + threadIdx.x;
    if (i >= npix) return;

    // One pixel per thread; all 12 dwordx4 loads issued up front.
    const f32x4* dp = reinterpret_cast<const f32x4*>(dists + (size_t)i * 8);
    const f32x4* zp = reinterpret_cast<const f32x4*>(zbuf + (size_t)i * 8);
    const i32x4* pp = reinterpret_cast<const i32x4*>(pix + (size_t)i * 8);
    const f32x4* tp = reinterpret_cast<const f32x4*>(texels + (size_t)i * 24);

    f32x4 dv0 = dp[0], dv1 = dp[1];
    f32x4 zv0 = zp[0], zv1 = zp[1];
    i32x4 pv0 = pp[0], pv1 = pp[1];
    f32x4 t0 = tp[0], t1 = tp[1], t2 = tp[2], t3 = tp[3], t4 = tp[4], t5 = tp[5];

    const float zscale = 1.0f / (ZFARC - ZNEARC);

    float d[8] = {dv0.x, dv0.y, dv0.z, dv0.w, dv1.x, dv1.y, dv1.z, dv1.w};
    float z[8] = {zv0.x, zv0.y, zv0.z, zv0.w, zv1.x, zv1.y, zv1.z, zv1.w};
    int   p[8] = {pv0.x, pv0.y, pv0.z, pv0.w, pv1.x, pv1.y, pv1.z, pv1.w};

    float prob[8], zinv[8];
    float zmax = EPSV;
    float alpha = 1.0f;
    #pragma unroll
    for (int k = 0; k < 8; ++k) {
        const bool m = p[k] >= 0;
        const float pr = m ? 1.0f / (1.0f + __expf(d[k] * SIGMA_INV)) : 0.0f;
        prob[k] = pr;
        alpha *= (1.0f - pr);
        const float zi = m ? (ZFARC - z[k]) * zscale : 0.0f;
        zinv[k] = zi;
        zmax = fmaxf(zmax, zi);
    }

    const float delta = fmaxf(__expf((EPSV - zmax) * GAMMA_INV), EPSV);
    float denom = delta;
    float wn[8];
    #pragma unroll
    for (int k = 0; k < 8; ++k) {
        const float w = prob[k] * __expf((zinv[k] - zmax) * GAMMA_INV);
        wn[k] = w;
        denom += w;
    }
    const float inv = 1.0f / denom;

    const float tf[24] = {t0.x, t0.y, t0.z, t0.w, t1.x, t1.y, t1.z, t1.w,
                          t2.x, t2.y, t2.z, t2.w, t3.x, t3.y, t3.z, t3.w,
                          t4.x, t4.y, t4.z, t4.w, t5.x, t5.y, t5.z, t5.w};

    // BG = (1,1,1): rgb_c = (sum_k wn_k * tex_kc + delta) / denom
    float r = delta, g = delta, b = delta;
    #pragma unroll
    for (int k = 0; k < 8; ++k) {
        r += wn[k] * tf[k * 3 + 0];
        g += wn[k] * tf[k * 3 + 1];
        b += wn[k] * tf[k * 3 + 2];
    }

    f32x4 o;
    o.x = r * inv;
    o.y = g * inv;
    o.z = b * inv;
    o.w = 1.0f - alpha;
    __builtin_nontemporal_store(o, reinterpret_cast<f32x4*>(out) + i);
}

extern "C" void kernel_launch(void* const* d_in, const int* in_sizes, int n_in,
                              void* d_out, int out_size, void* d_ws, size_t ws_size,
                              hipStream_t stream) {
    const float* texels = (const float*)d_in[0];
    const float* dists  = (const float*)d_in[1];
    const float* zbuf   = (const float*)d_in[2];
    const int*   pix    = (const int*)d_in[3];
    float* out = (float*)d_out;

    const int npix = in_sizes[1] / 8;  // dists is [N,H,W,K=8]
    const int block = 256;
    const int grid = (npix + block - 1) / block;
    softblend_kernel<<<grid, block, 0, stream>>>(texels, dists, zbuf, pix, out, npix);
}